// Round 8
// baseline (166.234 us; speedup 1.0000x reference)
//
#include <hip/hip_runtime.h>
#include <hip/hip_bf16.h>

#define S 64
#define HF 128
#define WF 128
#define HW (HF * WF)
#define SSQ (S * S)
#define CCH 256
#define NBOX 128                      // B * N
#define CROPS_ELEMS (134217728)      // NBOX * CCH * S * S
#define CHG 16                        // channels per block (8 float2 groups)
#define NGRP (CCH / CHG)              // 16 channel-group blocks per quadrant
#define TILE_F2 3264                  // float2 slots (26.1 KB); worst quadrant tile 57x57=3249

// Barrier that waits ONLY on LDS ops (lgkmcnt); global stores stay in flight.
__device__ __forceinline__ void barrier_lds_only() {
    asm volatile("s_waitcnt lgkmcnt(0)\n\ts_barrier" ::: "memory");
}

// ---------------- Kernel A: per-box theta + M ----------------
__global__ void prep_kernel(const float* __restrict__ obb,
                            float* __restrict__ theta_ws,
                            float* __restrict__ m_out) {
    int i = blockIdx.x * blockDim.x + threadIdx.x;
    if (i >= NBOX) return;
    const float* o = obb + i * 5;
    float cx = o[0], cy = o[1], w = o[2], h = o[3], deg = o[4];
    float cxf = cx * 0.125f;
    float cyf = cy * 0.125f;
    float wf = fmaxf(w, 1.0f) * 1.25f * 0.125f;
    float hf = fmaxf(h, 1.0f) * 1.25f * 0.125f;
    float ang = deg * 0.017453292519943295f;  // deg2rad
    float c_ = cosf(ang);
    float s_ = sinf(ang);
    float sx = wf * (2.0f / (float)WF);
    float sy = hf * (2.0f / (float)HF);
    float tx = cxf * (2.0f / (float)WF) - 1.0f;
    float ty = cyf * (2.0f / (float)HF) - 1.0f;
    float* th = theta_ws + i * 6;
    th[0] = c_ * sx;  th[1] = -s_ * sy; th[2] = tx;
    th[3] = s_ * sx;  th[4] = c_ * sy;  th[5] = ty;

    float A  = c_ * (wf / (float)S);
    float Bv = -s_ * (hf / (float)S);
    float A2 = s_ * (wf / (float)S);
    float B2 = c_ * (hf / (float)S);
    float Cx = cxf - 0.5f * (float)S * (A + Bv);
    float Cy = cyf - 0.5f * (float)S * (A2 + B2);
    float* m = m_out + i * 6;
    m[0] = A;  m[1] = Bv; m[2] = Cx;
    m[3] = A2; m[4] = B2; m[5] = Cy;
}

// ---------------- Kernel B: float2 (2-channel) LDS tile sampling ------------
// grid: NBOX * 4 quadrants * NGRP, XCD-swizzled. Block = 256 threads = 32 rows
// x 8 groups of 4 consecutive x (float4 stores). 8 iterations of 2 channels.
__global__ __launch_bounds__(256, 6) void sample_kernel(
        const float* __restrict__ feat,
        const float* __restrict__ theta,
        float* __restrict__ out) {
    __shared__ float2 tile[TILE_F2];

    // T1 XCD swizzle: 8192 blocks, 8 XCDs, round-robin dispatch (bid%8 = XCD).
    // bs = (bid%8)*1024 + bid/8 gives each XCD a contiguous 1024-block chunk
    // = 16 complete boxes -> each box's feature window becomes L2-resident
    // on one XCD instead of being pulled from L3 by all 8.
    const int b    = ((blockIdx.x & 7) << 10) | (blockIdx.x >> 3);
    const int grp  = b & 15;              // % NGRP
    const int quad = (b >> 4) & 3;
    const int box  = b >> 6;
    const int qx   = quad & 1;
    const int qy   = quad >> 1;
    const int tid  = threadIdx.x;

    const float* th = theta + box * 6;
    // feature-pixel affine: ix = ax*fx + bxc*fy + cx_, fx,fy in (-1,1)
    const float ax  = th[0] * 64.0f, bxc = th[1] * 64.0f, cx_ = th[2] * 64.0f + 63.5f;
    const float ay  = th[3] * 64.0f, byc = th[4] * 64.0f, cy_ = th[5] * 64.0f + 63.5f;

    // quadrant sample-coordinate bbox (+1 for bilinear upper corner)
    const float fcx = (float)qx - 0.5f;
    const float fcy = (float)qy - 0.5f;
    const float fh  = 31.0f / 64.0f;
    const float cxq = ax * fcx + bxc * fcy + cx_;
    const float cyq = ay * fcx + byc * fcy + cy_;
    const float hxq = (fabsf(ax) + fabsf(bxc)) * fh;
    const float hyq = (fabsf(ay) + fabsf(byc)) * fh;
    const int tx0 = min(max((int)floorf(cxq - hxq), 0), WF - 1);
    const int tx1 = min(max((int)floorf(cxq + hxq) + 1, 0), WF - 1);
    const int ty0 = min(max((int)floorf(cyq - hyq), 0), HF - 1);
    const int ty1 = min(max((int)floorf(cyq + hyq) + 1, 0), HF - 1);
    const int tw  = tx1 - tx0 + 1;
    const int thh = ty1 - ty0 + 1;
    const int twp = tw | 1;               // odd float2-slot row stride
    const int n   = tw * thh;

    // this thread's 4 consecutive-x pixels
    const int r     = tid >> 3;           // 0..31
    const int g     = tid & 7;            // 0..7
    const int y     = (qy << 5) + r;
    const int xbase = (qx << 5) + (g << 2);

    int   pk [4];
    float W00[4], W10[4], W01[4], W11[4];
    {
        float fy = (float)(2 * y + 1) * 0.015625f - 1.0f;
#pragma unroll
        for (int j = 0; j < 4; ++j) {
            int x = xbase + j;
            float fx = (float)(2 * x + 1) * 0.015625f - 1.0f;
            float ix = ax * fx + bxc * fy + cx_;
            float iy = ay * fx + byc * fy + cy_;
            float x0f = floorf(ix), y0f = floorf(iy);
            int x0 = (int)x0f, y0 = (int)y0f;
            float wx1 = ix - x0f, wy1 = iy - y0f;
            float wx0 = 1.0f - wx1, wy0 = 1.0f - wy1;
            bool vx0 = (x0 >= 0) & (x0 < WF);
            bool vx1 = (x0 >= -1) & (x0 < WF - 1);
            bool vy0 = (y0 >= 0) & (y0 < HF);
            bool vy1 = (y0 >= -1) & (y0 < HF - 1);
            W00[j] = (vx0 & vy0) ? wx0 * wy0 : 0.0f;
            W10[j] = (vx1 & vy0) ? wx1 * wy0 : 0.0f;
            W01[j] = (vx0 & vy1) ? wx0 * wy1 : 0.0f;
            W11[j] = (vx1 & vy1) ? wx1 * wy1 : 0.0f;
            int x0c = min(max(x0, 0), WF - 1) - tx0;
            int y0c = min(max(y0, 0), HF - 1) - ty0;
            int x1c = min(max(x0 + 1, 0), WF - 1) - tx0;
            int y1c = min(max(y0 + 1, 0), HF - 1) - ty0;
            int xs = x1c - x0c;           // 0 or 1
            int ys = y1c - y0c;           // 0 or 1
            pk[j] = (y0c * twp + x0c) | (xs << 16) | (ys << 17);
        }
    }

    // tile-loader walking state (no division in the channel loop)
    const int qy0_ = tid / tw;
    const int qx0_ = tid - qy0_ * tw;
    const int kq   = 256 / tw;
    const int rq   = 256 - kq * tw;
    const int lidx0 = qy0_ * twp + qx0_;
    const int gidx0 = (ty0 + qy0_) * WF + tx0 + qx0_;
    const int stepL = kq * twp + rq;
    const int stepG = (kq << 7) + rq;

    const float* fmb = feat + (size_t)(box >> 6) * (size_t)(CCH * HW)
                            + (size_t)(grp * CHG) * HW;
    float* ob = out + (size_t)box * (size_t)(CCH * SSQ)
                    + (size_t)(grp * CHG) * SSQ + y * S + xbase;

    for (int cg = 0; cg < CHG / 2; ++cg) {
        const float* fc = fmb + (size_t)(2 * cg) * HW;
        // ---- stage tile: 2 channels interleaved as float2 ----
        {
            int qx_ = qx0_, lidx = lidx0, gidx = gidx0;
            for (int q = tid; q < n; q += 256) {
                float2 t;
                t.x = fc[gidx];
                t.y = fc[gidx + HW];
                tile[lidx] = t;
                qx_ += rq; lidx += stepL; gidx += stepG;
                if (qx_ >= tw) { qx_ -= tw; lidx += twp - tw; gidx += WF - tw; }
            }
        }
        barrier_lds_only();
        // ---- sample 4 consecutive px x 2 channels, two float4 stores ----
        float4 v0, v1;
        float* vp0 = &v0.x;
        float* vp1 = &v1.x;
#pragma unroll
        for (int j = 0; j < 4; ++j) {
            int p   = pk[j];
            int a00 = p & 0xFFFF;
            int xs  = (p >> 16) & 1;
            int a01 = a00 + (((p >> 17) & 1) ? twp : 0);
            float2 c00 = tile[a00];
            float2 c10 = tile[a00 + xs];
            float2 c01 = tile[a01];
            float2 c11 = tile[a01 + xs];
            vp0[j] = c00.x * W00[j] + c10.x * W10[j] + c01.x * W01[j] + c11.x * W11[j];
            vp1[j] = c00.y * W00[j] + c10.y * W10[j] + c01.y * W01[j] + c11.y * W11[j];
        }
        float* oc = ob + (size_t)(2 * cg) * SSQ;
        *reinterpret_cast<float4*>(oc)       = v0;
        *reinterpret_cast<float4*>(oc + SSQ) = v1;
        barrier_lds_only();
    }
}

extern "C" void kernel_launch(void* const* d_in, const int* in_sizes, int n_in,
                              void* d_out, int out_size, void* d_ws, size_t ws_size,
                              hipStream_t stream) {
    const float* feat = (const float*)d_in[0];
    const float* obb  = (const float*)d_in[1];
    float* out = (float*)d_out;
    float* theta_ws = (float*)d_ws;
    float* m_out = out + CROPS_ELEMS;

    prep_kernel<<<1, 128, 0, stream>>>(obb, theta_ws, m_out);
    sample_kernel<<<NBOX * 4 * NGRP, 256, 0, stream>>>(feat, theta_ws, out);
}

// Round 9
// 142.582 us; speedup vs baseline: 1.1659x; 1.1659x over previous
//
#include <hip/hip_runtime.h>
#include <hip/hip_bf16.h>

#define S 64
#define HF 128
#define WF 128
#define HW (HF * WF)
#define SSQ (S * S)
#define CCH 256
#define NBOX 128                      // B * N
#define CROPS_ELEMS (134217728)      // NBOX * CCH * S * S
#define CHG 16                        // channels per block (4 float4 groups)
#define NGRP (CCH / CHG)              // 16 channel-group blocks per quadrant
#define TILE_F4 3264                  // float4 slots (52.2 KB); worst quadrant tile 57x57=3249

// Barrier that waits ONLY on LDS ops (lgkmcnt); global stores stay in flight.
__device__ __forceinline__ void barrier_lds_only() {
    asm volatile("s_waitcnt lgkmcnt(0)\n\ts_barrier" ::: "memory");
}

// ---------------- Kernel A: per-box theta + M ----------------
__global__ void prep_kernel(const float* __restrict__ obb,
                            float* __restrict__ theta_ws,
                            float* __restrict__ m_out) {
    int i = blockIdx.x * blockDim.x + threadIdx.x;
    if (i >= NBOX) return;
    const float* o = obb + i * 5;
    float cx = o[0], cy = o[1], w = o[2], h = o[3], deg = o[4];
    float cxf = cx * 0.125f;
    float cyf = cy * 0.125f;
    float wf = fmaxf(w, 1.0f) * 1.25f * 0.125f;
    float hf = fmaxf(h, 1.0f) * 1.25f * 0.125f;
    float ang = deg * 0.017453292519943295f;  // deg2rad
    float c_ = cosf(ang);
    float s_ = sinf(ang);
    float sx = wf * (2.0f / (float)WF);
    float sy = hf * (2.0f / (float)HF);
    float tx = cxf * (2.0f / (float)WF) - 1.0f;
    float ty = cyf * (2.0f / (float)HF) - 1.0f;
    float* th = theta_ws + i * 6;
    th[0] = c_ * sx;  th[1] = -s_ * sy; th[2] = tx;
    th[3] = s_ * sx;  th[4] = c_ * sy;  th[5] = ty;

    float A  = c_ * (wf / (float)S);
    float Bv = -s_ * (hf / (float)S);
    float A2 = s_ * (wf / (float)S);
    float B2 = c_ * (hf / (float)S);
    float Cx = cxf - 0.5f * (float)S * (A + Bv);
    float Cy = cyf - 0.5f * (float)S * (A2 + B2);
    float* m = m_out + i * 6;
    m[0] = A;  m[1] = Bv; m[2] = Cx;
    m[3] = A2; m[4] = B2; m[5] = Cy;
}

// ---------------- Kernel B: float4 (4-channel) LDS tile sampling ------------
// grid: NBOX * 4 quadrants * NGRP. Block = 256 threads = 32 rows x 8 groups
// of 4 consecutive x (float4 stores). 4 iterations of 4 channels (float4 tile,
// ds_read_b128 gathers -> half the scattered LDS read instructions of R4).
__global__ __launch_bounds__(256, 3) void sample_kernel(
        const float* __restrict__ feat,
        const float* __restrict__ theta,
        float* __restrict__ out) {
    __shared__ float4 tile[TILE_F4];

    const int b    = blockIdx.x;
    const int grp  = b & 15;              // % NGRP
    const int quad = (b >> 4) & 3;
    const int box  = b >> 6;
    const int qx   = quad & 1;
    const int qy   = quad >> 1;
    const int tid  = threadIdx.x;

    const float* th = theta + box * 6;
    // feature-pixel affine: ix = ax*fx + bxc*fy + cx_, fx,fy in (-1,1)
    const float ax  = th[0] * 64.0f, bxc = th[1] * 64.0f, cx_ = th[2] * 64.0f + 63.5f;
    const float ay  = th[3] * 64.0f, byc = th[4] * 64.0f, cy_ = th[5] * 64.0f + 63.5f;

    // quadrant sample-coordinate bbox (+1 for bilinear upper corner)
    const float fcx = (float)qx - 0.5f;
    const float fcy = (float)qy - 0.5f;
    const float fh  = 31.0f / 64.0f;
    const float cxq = ax * fcx + bxc * fcy + cx_;
    const float cyq = ay * fcx + byc * fcy + cy_;
    const float hxq = (fabsf(ax) + fabsf(bxc)) * fh;
    const float hyq = (fabsf(ay) + fabsf(byc)) * fh;
    const int tx0 = min(max((int)floorf(cxq - hxq), 0), WF - 1);
    const int tx1 = min(max((int)floorf(cxq + hxq) + 1, 0), WF - 1);
    const int ty0 = min(max((int)floorf(cyq - hyq), 0), HF - 1);
    const int ty1 = min(max((int)floorf(cyq + hyq) + 1, 0), HF - 1);
    const int tw  = tx1 - tx0 + 1;
    const int thh = ty1 - ty0 + 1;
    const int twp = tw | 1;               // odd float4-slot row stride
    const int n   = tw * thh;

    // this thread's 4 consecutive-x pixels
    const int r     = tid >> 3;           // 0..31
    const int g     = tid & 7;            // 0..7
    const int y     = (qy << 5) + r;
    const int xbase = (qx << 5) + (g << 2);

    int   pk [4];
    float W00[4], W10[4], W01[4], W11[4];
    {
        float fy = (float)(2 * y + 1) * 0.015625f - 1.0f;
#pragma unroll
        for (int j = 0; j < 4; ++j) {
            int x = xbase + j;
            float fx = (float)(2 * x + 1) * 0.015625f - 1.0f;
            float ix = ax * fx + bxc * fy + cx_;
            float iy = ay * fx + byc * fy + cy_;
            float x0f = floorf(ix), y0f = floorf(iy);
            int x0 = (int)x0f, y0 = (int)y0f;
            float wx1 = ix - x0f, wy1 = iy - y0f;
            float wx0 = 1.0f - wx1, wy0 = 1.0f - wy1;
            bool vx0 = (x0 >= 0) & (x0 < WF);
            bool vx1 = (x0 >= -1) & (x0 < WF - 1);
            bool vy0 = (y0 >= 0) & (y0 < HF);
            bool vy1 = (y0 >= -1) & (y0 < HF - 1);
            W00[j] = (vx0 & vy0) ? wx0 * wy0 : 0.0f;
            W10[j] = (vx1 & vy0) ? wx1 * wy0 : 0.0f;
            W01[j] = (vx0 & vy1) ? wx0 * wy1 : 0.0f;
            W11[j] = (vx1 & vy1) ? wx1 * wy1 : 0.0f;
            int x0c = min(max(x0, 0), WF - 1) - tx0;
            int y0c = min(max(y0, 0), HF - 1) - ty0;
            int x1c = min(max(x0 + 1, 0), WF - 1) - tx0;
            int y1c = min(max(y0 + 1, 0), HF - 1) - ty0;
            int xs = x1c - x0c;           // 0 or 1
            int ys = y1c - y0c;           // 0 or 1
            pk[j] = (y0c * twp + x0c) | (xs << 16) | (ys << 17);
        }
    }

    // tile-loader walking state (no division in the channel loop)
    const int qy0_ = tid / tw;
    const int qx0_ = tid - qy0_ * tw;
    const int kq   = 256 / tw;
    const int rq   = 256 - kq * tw;
    const int lidx0 = qy0_ * twp + qx0_;
    const int gidx0 = (ty0 + qy0_) * WF + tx0 + qx0_;
    const int stepL = kq * twp + rq;
    const int stepG = (kq << 7) + rq;

    const float* fmb = feat + (size_t)(box >> 6) * (size_t)(CCH * HW)
                            + (size_t)(grp * CHG) * HW;
    float* ob = out + (size_t)box * (size_t)(CCH * SSQ)
                    + (size_t)(grp * CHG) * SSQ + y * S + xbase;

    for (int cg = 0; cg < CHG / 4; ++cg) {
        const float* fc = fmb + (size_t)(4 * cg) * HW;
        // ---- stage tile: 4 channels interleaved as float4 ----
        {
            int qx_ = qx0_, lidx = lidx0, gidx = gidx0;
            for (int q = tid; q < n; q += 256) {
                float4 t;
                t.x = fc[gidx];
                t.y = fc[gidx + HW];
                t.z = fc[gidx + 2 * HW];
                t.w = fc[gidx + 3 * HW];
                tile[lidx] = t;
                qx_ += rq; lidx += stepL; gidx += stepG;
                if (qx_ >= tw) { qx_ -= tw; lidx += twp - tw; gidx += WF - tw; }
            }
        }
        barrier_lds_only();
        // ---- sample 4 consecutive px x 4 channels, four float4 stores ----
        float4 v0, v1, v2, v3;
        float* vp0 = &v0.x;
        float* vp1 = &v1.x;
        float* vp2 = &v2.x;
        float* vp3 = &v3.x;
#pragma unroll
        for (int j = 0; j < 4; ++j) {
            int p   = pk[j];
            int a00 = p & 0xFFFF;
            int xs  = (p >> 16) & 1;
            int a01 = a00 + (((p >> 17) & 1) ? twp : 0);
            float4 c00 = tile[a00];
            float4 c10 = tile[a00 + xs];
            float4 c01 = tile[a01];
            float4 c11 = tile[a01 + xs];
            vp0[j] = c00.x * W00[j] + c10.x * W10[j] + c01.x * W01[j] + c11.x * W11[j];
            vp1[j] = c00.y * W00[j] + c10.y * W10[j] + c01.y * W01[j] + c11.y * W11[j];
            vp2[j] = c00.z * W00[j] + c10.z * W10[j] + c01.z * W01[j] + c11.z * W11[j];
            vp3[j] = c00.w * W00[j] + c10.w * W10[j] + c01.w * W01[j] + c11.w * W11[j];
        }
        float* oc = ob + (size_t)(4 * cg) * SSQ;
        *reinterpret_cast<float4*>(oc)           = v0;
        *reinterpret_cast<float4*>(oc + SSQ)     = v1;
        *reinterpret_cast<float4*>(oc + 2 * SSQ) = v2;
        *reinterpret_cast<float4*>(oc + 3 * SSQ) = v3;
        barrier_lds_only();
    }
}

extern "C" void kernel_launch(void* const* d_in, const int* in_sizes, int n_in,
                              void* d_out, int out_size, void* d_ws, size_t ws_size,
                              hipStream_t stream) {
    const float* feat = (const float*)d_in[0];
    const float* obb  = (const float*)d_in[1];
    float* out = (float*)d_out;
    float* theta_ws = (float*)d_ws;
    float* m_out = out + CROPS_ELEMS;

    prep_kernel<<<1, 128, 0, stream>>>(obb, theta_ws, m_out);
    sample_kernel<<<NBOX * 4 * NGRP, 256, 0, stream>>>(feat, theta_ws, out);
}

// Round 10
// 119.916 us; speedup vs baseline: 1.3863x; 1.1890x over previous
//
#include <hip/hip_runtime.h>
#include <hip/hip_bf16.h>

#define S 64
#define HF 128
#define WF 128
#define HW (HF * WF)
#define SSQ (S * S)
#define CCH 256
#define NBOX 128                      // B * N
#define CROPS_ELEMS (134217728)      // NBOX * CCH * S * S
#define CHG 16                        // channels per block (2 phases of 8)
#define NGRP (CCH / CHG)              // 16 channel-group blocks per quadrant
#define TILE_SLOTS 3264               // uint4 slots (52.2 KB); worst quadrant tile 57x57=3249

// Barrier that waits ONLY on LDS ops (lgkmcnt); global stores stay in flight.
__device__ __forceinline__ void barrier_lds_only() {
    asm volatile("s_waitcnt lgkmcnt(0)\n\ts_barrier" ::: "memory");
}

// pack two f32 -> bf16x2 dword (round-to-nearest-ish via +0x8000 before truncate)
__device__ __forceinline__ unsigned int pack_bf16x2(float a, float b) {
    unsigned int au = __float_as_uint(a) + 0x8000u;
    unsigned int bu = __float_as_uint(b) + 0x8000u;
    return (au >> 16) | (bu & 0xFFFF0000u);
}
// unpack bf16x2 dword
__device__ __forceinline__ float bf_lo(unsigned int u) { return __uint_as_float(u << 16); }
__device__ __forceinline__ float bf_hi(unsigned int u) { return __uint_as_float(u & 0xFFFF0000u); }

// ---------------- Kernel A: per-box theta + M ----------------
__global__ void prep_kernel(const float* __restrict__ obb,
                            float* __restrict__ theta_ws,
                            float* __restrict__ m_out) {
    int i = blockIdx.x * blockDim.x + threadIdx.x;
    if (i >= NBOX) return;
    const float* o = obb + i * 5;
    float cx = o[0], cy = o[1], w = o[2], h = o[3], deg = o[4];
    float cxf = cx * 0.125f;
    float cyf = cy * 0.125f;
    float wf = fmaxf(w, 1.0f) * 1.25f * 0.125f;
    float hf = fmaxf(h, 1.0f) * 1.25f * 0.125f;
    float ang = deg * 0.017453292519943295f;  // deg2rad
    float c_ = cosf(ang);
    float s_ = sinf(ang);
    float sx = wf * (2.0f / (float)WF);
    float sy = hf * (2.0f / (float)HF);
    float tx = cxf * (2.0f / (float)WF) - 1.0f;
    float ty = cyf * (2.0f / (float)HF) - 1.0f;
    float* th = theta_ws + i * 6;
    th[0] = c_ * sx;  th[1] = -s_ * sy; th[2] = tx;
    th[3] = s_ * sx;  th[4] = c_ * sy;  th[5] = ty;

    float A  = c_ * (wf / (float)S);
    float Bv = -s_ * (hf / (float)S);
    float A2 = s_ * (wf / (float)S);
    float B2 = c_ * (hf / (float)S);
    float Cx = cxf - 0.5f * (float)S * (A + Bv);
    float Cy = cyf - 0.5f * (float)S * (A2 + B2);
    float* m = m_out + i * 6;
    m[0] = A;  m[1] = Bv; m[2] = Cx;
    m[3] = A2; m[4] = B2; m[5] = Cy;
}

// ------------- Kernel B: bf16 8-channel b128 LDS tile sampling --------------
// grid: NBOX * 4 quadrants * NGRP. Block = 256 threads = 32 rows x 8 groups
// of 4 consecutive x (float4 stores). 2 phases of 8 channels; tile slot =
// uint4 = 8 bf16 channels -> 4 ds_read_b128 serve 8 channels per pixel.
__global__ __launch_bounds__(256, 3) void sample_kernel(
        const float* __restrict__ feat,
        const float* __restrict__ theta,
        float* __restrict__ out) {
    __shared__ uint4 tile[TILE_SLOTS];

    const int b    = blockIdx.x;
    const int grp  = b & 15;              // % NGRP
    const int quad = (b >> 4) & 3;
    const int box  = b >> 6;
    const int qx   = quad & 1;
    const int qy   = quad >> 1;
    const int tid  = threadIdx.x;

    const float* th = theta + box * 6;
    // feature-pixel affine: ix = ax*fx + bxc*fy + cx_, fx,fy in (-1,1)
    const float ax  = th[0] * 64.0f, bxc = th[1] * 64.0f, cx_ = th[2] * 64.0f + 63.5f;
    const float ay  = th[3] * 64.0f, byc = th[4] * 64.0f, cy_ = th[5] * 64.0f + 63.5f;

    // quadrant sample-coordinate bbox (+1 for bilinear upper corner)
    const float fcx = (float)qx - 0.5f;
    const float fcy = (float)qy - 0.5f;
    const float fh  = 31.0f / 64.0f;
    const float cxq = ax * fcx + bxc * fcy + cx_;
    const float cyq = ay * fcx + byc * fcy + cy_;
    const float hxq = (fabsf(ax) + fabsf(bxc)) * fh;
    const float hyq = (fabsf(ay) + fabsf(byc)) * fh;
    const int tx0 = min(max((int)floorf(cxq - hxq), 0), WF - 1);
    const int tx1 = min(max((int)floorf(cxq + hxq) + 1, 0), WF - 1);
    const int ty0 = min(max((int)floorf(cyq - hyq), 0), HF - 1);
    const int ty1 = min(max((int)floorf(cyq + hyq) + 1, 0), HF - 1);
    const int tw  = tx1 - tx0 + 1;
    const int thh = ty1 - ty0 + 1;
    const int twp = tw | 1;               // odd slot row stride
    const int n   = tw * thh;

    // this thread's 4 consecutive-x pixels
    const int r     = tid >> 3;           // 0..31
    const int g     = tid & 7;            // 0..7
    const int y     = (qy << 5) + r;
    const int xbase = (qx << 5) + (g << 2);

    int   pk [4];
    float W00[4], W10[4], W01[4], W11[4];
    {
        float fy = (float)(2 * y + 1) * 0.015625f - 1.0f;
#pragma unroll
        for (int j = 0; j < 4; ++j) {
            int x = xbase + j;
            float fx = (float)(2 * x + 1) * 0.015625f - 1.0f;
            float ix = ax * fx + bxc * fy + cx_;
            float iy = ay * fx + byc * fy + cy_;
            float x0f = floorf(ix), y0f = floorf(iy);
            int x0 = (int)x0f, y0 = (int)y0f;
            float wx1 = ix - x0f, wy1 = iy - y0f;
            float wx0 = 1.0f - wx1, wy0 = 1.0f - wy1;
            bool vx0 = (x0 >= 0) & (x0 < WF);
            bool vx1 = (x0 >= -1) & (x0 < WF - 1);
            bool vy0 = (y0 >= 0) & (y0 < HF);
            bool vy1 = (y0 >= -1) & (y0 < HF - 1);
            W00[j] = (vx0 & vy0) ? wx0 * wy0 : 0.0f;
            W10[j] = (vx1 & vy0) ? wx1 * wy0 : 0.0f;
            W01[j] = (vx0 & vy1) ? wx0 * wy1 : 0.0f;
            W11[j] = (vx1 & vy1) ? wx1 * wy1 : 0.0f;
            int x0c = min(max(x0, 0), WF - 1) - tx0;
            int y0c = min(max(y0, 0), HF - 1) - ty0;
            int x1c = min(max(x0 + 1, 0), WF - 1) - tx0;
            int y1c = min(max(y0 + 1, 0), HF - 1) - ty0;
            int xs = x1c - x0c;           // 0 or 1
            int ys = y1c - y0c;           // 0 or 1
            pk[j] = (y0c * twp + x0c) | (xs << 16) | (ys << 17);
        }
    }

    // tile-loader walking state (no division in the channel loop)
    const int qy0_ = tid / tw;
    const int qx0_ = tid - qy0_ * tw;
    const int kq   = 256 / tw;
    const int rq   = 256 - kq * tw;
    const int lidx0 = qy0_ * twp + qx0_;
    const int gidx0 = (ty0 + qy0_) * WF + tx0 + qx0_;
    const int stepL = kq * twp + rq;
    const int stepG = (kq << 7) + rq;

    const float* fmb = feat + (size_t)(box >> 6) * (size_t)(CCH * HW)
                            + (size_t)(grp * CHG) * HW;
    float* ob = out + (size_t)box * (size_t)(CCH * SSQ)
                    + (size_t)(grp * CHG) * SSQ + y * S + xbase;

#pragma unroll
    for (int ph = 0; ph < 2; ++ph) {
        const float* fc = fmb + (size_t)(8 * ph) * HW;
        // ---- stage tile: 8 channels packed as bf16 in uint4 ----
        {
            int qx_ = qx0_, lidx = lidx0, gidx = gidx0;
            for (int q = tid; q < n; q += 256) {
                uint4 t;
                t.x = pack_bf16x2(fc[gidx],          fc[gidx + HW]);
                t.y = pack_bf16x2(fc[gidx + 2 * HW], fc[gidx + 3 * HW]);
                t.z = pack_bf16x2(fc[gidx + 4 * HW], fc[gidx + 5 * HW]);
                t.w = pack_bf16x2(fc[gidx + 6 * HW], fc[gidx + 7 * HW]);
                tile[lidx] = t;
                qx_ += rq; lidx += stepL; gidx += stepG;
                if (qx_ >= tw) { qx_ -= tw; lidx += twp - tw; gidx += WF - tw; }
            }
        }
        barrier_lds_only();
        // ---- sample 4 consecutive px x 8 channels, eight float4 stores ----
        float4 v0, v1, v2, v3, v4, v5, v6, v7;
        float* vp[8] = { &v0.x, &v1.x, &v2.x, &v3.x, &v4.x, &v5.x, &v6.x, &v7.x };
#pragma unroll
        for (int j = 0; j < 4; ++j) {
            int p   = pk[j];
            int a00 = p & 0xFFFF;
            int xs  = (p >> 16) & 1;
            int a01 = a00 + (((p >> 17) & 1) ? twp : 0);
            uint4 c00 = tile[a00];
            uint4 c10 = tile[a00 + xs];
            uint4 c01 = tile[a01];
            uint4 c11 = tile[a01 + xs];
            float w00 = W00[j], w10 = W10[j], w01 = W01[j], w11 = W11[j];
            vp[0][j] = bf_lo(c00.x)*w00 + bf_lo(c10.x)*w10 + bf_lo(c01.x)*w01 + bf_lo(c11.x)*w11;
            vp[1][j] = bf_hi(c00.x)*w00 + bf_hi(c10.x)*w10 + bf_hi(c01.x)*w01 + bf_hi(c11.x)*w11;
            vp[2][j] = bf_lo(c00.y)*w00 + bf_lo(c10.y)*w10 + bf_lo(c01.y)*w01 + bf_lo(c11.y)*w11;
            vp[3][j] = bf_hi(c00.y)*w00 + bf_hi(c10.y)*w10 + bf_hi(c01.y)*w01 + bf_hi(c11.y)*w11;
            vp[4][j] = bf_lo(c00.z)*w00 + bf_lo(c10.z)*w10 + bf_lo(c01.z)*w01 + bf_lo(c11.z)*w11;
            vp[5][j] = bf_hi(c00.z)*w00 + bf_hi(c10.z)*w10 + bf_hi(c01.z)*w01 + bf_hi(c11.z)*w11;
            vp[6][j] = bf_lo(c00.w)*w00 + bf_lo(c10.w)*w10 + bf_lo(c01.w)*w01 + bf_lo(c11.w)*w11;
            vp[7][j] = bf_hi(c00.w)*w00 + bf_hi(c10.w)*w10 + bf_hi(c01.w)*w01 + bf_hi(c11.w)*w11;
        }
        float* oc = ob + (size_t)(8 * ph) * SSQ;
        *reinterpret_cast<float4*>(oc)           = v0;
        *reinterpret_cast<float4*>(oc + SSQ)     = v1;
        *reinterpret_cast<float4*>(oc + 2 * SSQ) = v2;
        *reinterpret_cast<float4*>(oc + 3 * SSQ) = v3;
        *reinterpret_cast<float4*>(oc + 4 * SSQ) = v4;
        *reinterpret_cast<float4*>(oc + 5 * SSQ) = v5;
        *reinterpret_cast<float4*>(oc + 6 * SSQ) = v6;
        *reinterpret_cast<float4*>(oc + 7 * SSQ) = v7;
        barrier_lds_only();
    }
}

extern "C" void kernel_launch(void* const* d_in, const int* in_sizes, int n_in,
                              void* d_out, int out_size, void* d_ws, size_t ws_size,
                              hipStream_t stream) {
    const float* feat = (const float*)d_in[0];
    const float* obb  = (const float*)d_in[1];
    float* out = (float*)d_out;
    float* theta_ws = (float*)d_ws;
    float* m_out = out + CROPS_ELEMS;

    prep_kernel<<<1, 128, 0, stream>>>(obb, theta_ws, m_out);
    sample_kernel<<<NBOX * 4 * NGRP, 256, 0, stream>>>(feat, theta_ws, out);
}

// Round 11
// 118.409 us; speedup vs baseline: 1.4039x; 1.0127x over previous
//
#include <hip/hip_runtime.h>
#include <hip/hip_bf16.h>
#include <hip/hip_fp16.h>

#define S 64
#define HF 128
#define WF 128
#define HW (HF * WF)
#define SSQ (S * S)
#define CCH 256
#define NBOX 128                      // B * N
#define CROPS_ELEMS (134217728)      // NBOX * CCH * S * S
#define CHG 16                        // channels per block (2 phases of 8)
#define NGRP (CCH / CHG)              // 16 channel-group blocks per quadrant
#define TILE_SLOTS 3264               // 16B slots (52.2 KB); worst quadrant tile 57x57=3249

// Barrier that waits ONLY on LDS ops (lgkmcnt); global stores stay in flight.
__device__ __forceinline__ void barrier_lds_only() {
    asm volatile("s_waitcnt lgkmcnt(0)\n\ts_barrier" ::: "memory");
}

// 16-byte LDS slot: 8 channels as 4x half2
struct alignas(16) h2x4 { __half2 a, b, c, d; };

// ---------------- Kernel A: per-box theta + M ----------------
__global__ void prep_kernel(const float* __restrict__ obb,
                            float* __restrict__ theta_ws,
                            float* __restrict__ m_out) {
    int i = blockIdx.x * blockDim.x + threadIdx.x;
    if (i >= NBOX) return;
    const float* o = obb + i * 5;
    float cx = o[0], cy = o[1], w = o[2], h = o[3], deg = o[4];
    float cxf = cx * 0.125f;
    float cyf = cy * 0.125f;
    float wf = fmaxf(w, 1.0f) * 1.25f * 0.125f;
    float hf = fmaxf(h, 1.0f) * 1.25f * 0.125f;
    float ang = deg * 0.017453292519943295f;  // deg2rad
    float c_ = cosf(ang);
    float s_ = sinf(ang);
    float sx = wf * (2.0f / (float)WF);
    float sy = hf * (2.0f / (float)HF);
    float tx = cxf * (2.0f / (float)WF) - 1.0f;
    float ty = cyf * (2.0f / (float)HF) - 1.0f;
    float* th = theta_ws + i * 6;
    th[0] = c_ * sx;  th[1] = -s_ * sy; th[2] = tx;
    th[3] = s_ * sx;  th[4] = c_ * sy;  th[5] = ty;

    float A  = c_ * (wf / (float)S);
    float Bv = -s_ * (hf / (float)S);
    float A2 = s_ * (wf / (float)S);
    float B2 = c_ * (hf / (float)S);
    float Cx = cxf - 0.5f * (float)S * (A + Bv);
    float Cy = cyf - 0.5f * (float)S * (A2 + B2);
    float* m = m_out + i * 6;
    m[0] = A;  m[1] = Bv; m[2] = Cx;
    m[3] = A2; m[4] = B2; m[5] = Cy;
}

// ------------- Kernel B: f16 8-channel b128 LDS tile, packed-half2 math -----
// grid: NBOX * 4 quadrants * NGRP. Block = 256 threads = 32 rows x 8 groups
// of 4 consecutive x (float4 stores). 2 phases of 8 channels; tile slot =
// 8 f16 channels -> 4 ds_read_b128 + 16 pk_fma serve 8 channels per pixel.
__global__ __launch_bounds__(256, 3) void sample_kernel(
        const float* __restrict__ feat,
        const float* __restrict__ theta,
        float* __restrict__ out) {
    __shared__ h2x4 tile[TILE_SLOTS];

    const int b    = blockIdx.x;
    const int grp  = b & 15;              // % NGRP
    const int quad = (b >> 4) & 3;
    const int box  = b >> 6;
    const int qx   = quad & 1;
    const int qy   = quad >> 1;
    const int tid  = threadIdx.x;

    const float* th = theta + box * 6;
    // feature-pixel affine: ix = ax*fx + bxc*fy + cx_, fx,fy in (-1,1)
    const float ax  = th[0] * 64.0f, bxc = th[1] * 64.0f, cx_ = th[2] * 64.0f + 63.5f;
    const float ay  = th[3] * 64.0f, byc = th[4] * 64.0f, cy_ = th[5] * 64.0f + 63.5f;

    // quadrant sample-coordinate bbox (+1 for bilinear upper corner)
    const float fcx = (float)qx - 0.5f;
    const float fcy = (float)qy - 0.5f;
    const float fh  = 31.0f / 64.0f;
    const float cxq = ax * fcx + bxc * fcy + cx_;
    const float cyq = ay * fcx + byc * fcy + cy_;
    const float hxq = (fabsf(ax) + fabsf(bxc)) * fh;
    const float hyq = (fabsf(ay) + fabsf(byc)) * fh;
    const int tx0 = min(max((int)floorf(cxq - hxq), 0), WF - 1);
    const int tx1 = min(max((int)floorf(cxq + hxq) + 1, 0), WF - 1);
    const int ty0 = min(max((int)floorf(cyq - hyq), 0), HF - 1);
    const int ty1 = min(max((int)floorf(cyq + hyq) + 1, 0), HF - 1);
    const int tw  = tx1 - tx0 + 1;
    const int thh = ty1 - ty0 + 1;
    const int twp = tw | 1;               // odd slot row stride
    const int n   = tw * thh;

    // this thread's 4 consecutive-x pixels
    const int r     = tid >> 3;           // 0..31
    const int g     = tid & 7;            // 0..7
    const int y     = (qy << 5) + r;
    const int xbase = (qx << 5) + (g << 2);

    int     pk [4];
    __half2 W00h[4], W10h[4], W01h[4], W11h[4];
    {
        float fy = (float)(2 * y + 1) * 0.015625f - 1.0f;
#pragma unroll
        for (int j = 0; j < 4; ++j) {
            int x = xbase + j;
            float fx = (float)(2 * x + 1) * 0.015625f - 1.0f;
            float ix = ax * fx + bxc * fy + cx_;
            float iy = ay * fx + byc * fy + cy_;
            float x0f = floorf(ix), y0f = floorf(iy);
            int x0 = (int)x0f, y0 = (int)y0f;
            float wx1 = ix - x0f, wy1 = iy - y0f;
            float wx0 = 1.0f - wx1, wy0 = 1.0f - wy1;
            bool vx0 = (x0 >= 0) & (x0 < WF);
            bool vx1 = (x0 >= -1) & (x0 < WF - 1);
            bool vy0 = (y0 >= 0) & (y0 < HF);
            bool vy1 = (y0 >= -1) & (y0 < HF - 1);
            float W00 = (vx0 & vy0) ? wx0 * wy0 : 0.0f;
            float W10 = (vx1 & vy0) ? wx1 * wy0 : 0.0f;
            float W01 = (vx0 & vy1) ? wx0 * wy1 : 0.0f;
            float W11 = (vx1 & vy1) ? wx1 * wy1 : 0.0f;
            W00h[j] = __half2half2(__float2half_rn(W00));
            W10h[j] = __half2half2(__float2half_rn(W10));
            W01h[j] = __half2half2(__float2half_rn(W01));
            W11h[j] = __half2half2(__float2half_rn(W11));
            int x0c = min(max(x0, 0), WF - 1) - tx0;
            int y0c = min(max(y0, 0), HF - 1) - ty0;
            int x1c = min(max(x0 + 1, 0), WF - 1) - tx0;
            int y1c = min(max(y0 + 1, 0), HF - 1) - ty0;
            int xs = x1c - x0c;           // 0 or 1
            int ys = y1c - y0c;           // 0 or 1
            pk[j] = (y0c * twp + x0c) | (xs << 16) | (ys << 17);
        }
    }

    // tile-loader walking state (no division in the channel loop)
    const int qy0_ = tid / tw;
    const int qx0_ = tid - qy0_ * tw;
    const int kq   = 256 / tw;
    const int rq   = 256 - kq * tw;
    const int lidx0 = qy0_ * twp + qx0_;
    const int gidx0 = (ty0 + qy0_) * WF + tx0 + qx0_;
    const int stepL = kq * twp + rq;
    const int stepG = (kq << 7) + rq;

    const float* fmb = feat + (size_t)(box >> 6) * (size_t)(CCH * HW)
                            + (size_t)(grp * CHG) * HW;
    float* ob = out + (size_t)box * (size_t)(CCH * SSQ)
                    + (size_t)(grp * CHG) * SSQ + y * S + xbase;

#pragma unroll
    for (int ph = 0; ph < 2; ++ph) {
        const float* fc = fmb + (size_t)(8 * ph) * HW;
        // ---- stage tile: 8 channels packed as f16 (v_cvt_pkrtz_f16_f32) ----
        {
            int qx_ = qx0_, lidx = lidx0, gidx = gidx0;
            for (int q = tid; q < n; q += 256) {
                h2x4 t;
                t.a = __float22half2_rn(make_float2(fc[gidx],          fc[gidx + HW]));
                t.b = __float22half2_rn(make_float2(fc[gidx + 2 * HW], fc[gidx + 3 * HW]));
                t.c = __float22half2_rn(make_float2(fc[gidx + 4 * HW], fc[gidx + 5 * HW]));
                t.d = __float22half2_rn(make_float2(fc[gidx + 6 * HW], fc[gidx + 7 * HW]));
                tile[lidx] = t;
                qx_ += rq; lidx += stepL; gidx += stepG;
                if (qx_ >= tw) { qx_ -= tw; lidx += twp - tw; gidx += WF - tw; }
            }
        }
        barrier_lds_only();
        // ---- sample 4 consecutive px x 8 channels in packed half2 math ----
        float4 v0, v1, v2, v3, v4, v5, v6, v7;
        float* vp[8] = { &v0.x, &v1.x, &v2.x, &v3.x, &v4.x, &v5.x, &v6.x, &v7.x };
#pragma unroll
        for (int j = 0; j < 4; ++j) {
            int p   = pk[j];
            int a00 = p & 0xFFFF;
            int xs  = (p >> 16) & 1;
            int a01 = a00 + (((p >> 17) & 1) ? twp : 0);
            h2x4 c00 = tile[a00];
            h2x4 c10 = tile[a00 + xs];
            h2x4 c01 = tile[a01];
            h2x4 c11 = tile[a01 + xs];
            __half2 w00 = W00h[j], w10 = W10h[j], w01 = W01h[j], w11 = W11h[j];
            __half2 r0 = __hfma2(c00.a, w00, __hfma2(c10.a, w10,
                         __hfma2(c01.a, w01, __hmul2(c11.a, w11))));
            __half2 r1 = __hfma2(c00.b, w00, __hfma2(c10.b, w10,
                         __hfma2(c01.b, w01, __hmul2(c11.b, w11))));
            __half2 r2 = __hfma2(c00.c, w00, __hfma2(c10.c, w10,
                         __hfma2(c01.c, w01, __hmul2(c11.c, w11))));
            __half2 r3 = __hfma2(c00.d, w00, __hfma2(c10.d, w10,
                         __hfma2(c01.d, w01, __hmul2(c11.d, w11))));
            float2 f0 = __half22float2(r0);
            float2 f1 = __half22float2(r1);
            float2 f2 = __half22float2(r2);
            float2 f3 = __half22float2(r3);
            vp[0][j] = f0.x; vp[1][j] = f0.y;
            vp[2][j] = f1.x; vp[3][j] = f1.y;
            vp[4][j] = f2.x; vp[5][j] = f2.y;
            vp[6][j] = f3.x; vp[7][j] = f3.y;
        }
        float* oc = ob + (size_t)(8 * ph) * SSQ;
        *reinterpret_cast<float4*>(oc)           = v0;
        *reinterpret_cast<float4*>(oc + SSQ)     = v1;
        *reinterpret_cast<float4*>(oc + 2 * SSQ) = v2;
        *reinterpret_cast<float4*>(oc + 3 * SSQ) = v3;
        *reinterpret_cast<float4*>(oc + 4 * SSQ) = v4;
        *reinterpret_cast<float4*>(oc + 5 * SSQ) = v5;
        *reinterpret_cast<float4*>(oc + 6 * SSQ) = v6;
        *reinterpret_cast<float4*>(oc + 7 * SSQ) = v7;
        barrier_lds_only();
    }
}

extern "C" void kernel_launch(void* const* d_in, const int* in_sizes, int n_in,
                              void* d_out, int out_size, void* d_ws, size_t ws_size,
                              hipStream_t stream) {
    const float* feat = (const float*)d_in[0];
    const float* obb  = (const float*)d_in[1];
    float* out = (float*)d_out;
    float* theta_ws = (float*)d_ws;
    float* m_out = out + CROPS_ELEMS;

    prep_kernel<<<1, 128, 0, stream>>>(obb, theta_ws, m_out);
    sample_kernel<<<NBOX * 4 * NGRP, 256, 0, stream>>>(feat, theta_ws, out);
}